// Round 1
// 412.331 us; speedup vs baseline: 1.0501x; 1.0501x over previous
//
#include <hip/hip_runtime.h>
#include <hip/hip_bf16.h>
#include <stdint.h>

// MoE gate: logits = r @ W^T + b ; soft = softmax(logits) ; hard = top8-renorm
// r: (32768, 2048) fp32, W: (64, 2048) fp32, b: (64,) fp32
// d_out: [hard (32768*64) | soft (32768*64)] fp32
//
// Precision: exact bf16^3 split of both operands, 6 MFMA terms in 3 scale-
// class accumulators (verified: absmax 0.00195 vs 0.01625 thr).
//
// Round-4 theory: round-3 was latency-bound (MfmaUtil 11%, VALU 24%, HBM 11%,
// occupancy 22%) — grid capped concurrency at 8 waves/CU and every k-step
// __syncthreads drains vmcnt(0). This round: K-split 8-wave blocks (16
// waves/CU), LDS union (bstage | lg, 48 KB), and a pre-permuted W staging
// image so each staging gload_lds reads a contiguous 1 KB per wave.

#define D_DIM 2048
#define E_DIM 64
#define B_DIM 32768
#define TOPK 8

typedef __bf16 bf16x8 __attribute__((ext_vector_type(8)));
typedef float f32x4 __attribute__((ext_vector_type(4)));

// ---- prep: W fp32 -> per-kstep staging image ----
// P[ks][split][2048 bf16] = 12 KB per kstep. Element (s, u*8+j) = split_s of
// W[e = u>>2][ks*32 + (u&3)*8 + j] — byte-identical to the LDS image moe_gate
// consumes, so staging loads are lane-contiguous (1 KB per wave instruction).
__global__ __launch_bounds__(256) void w_prep(const float* __restrict__ W,
                                              __bf16* __restrict__ P) {
    const int K = blockIdx.x;    // kstep 0..63
    const int u = threadIdx.x;   // slot 0..255
    const float* src = W + (size_t)(u >> 2) * D_DIM + K * 32 + (u & 3) * 8;
    __bf16* dst = P + (size_t)K * 6144 + u * 8;
    bf16x8 o1, o2, o3;
    #pragma unroll
    for (int j = 0; j < 8; ++j) {
        float x  = src[j];
        __bf16 h1 = (__bf16)x;
        float r1 = x - (float)h1;          // exact
        __bf16 h2 = (__bf16)r1;
        float r2 = r1 - (float)h2;         // exact
        o1[j] = h1; o2[j] = h2; o3[j] = (__bf16)r2;
    }
    *(bf16x8*)(dst)        = o1;
    *(bf16x8*)(dst + 2048) = o2;
    *(bf16x8*)(dst + 4096) = o3;
}

// async 16B global -> LDS (per lane; LDS dest = wave-uniform base + lane*16)
__device__ __forceinline__ void gload_lds16(const void* g, void* s) {
    __builtin_amdgcn_global_load_lds(
        (const __attribute__((address_space(1))) unsigned int*)g,
        (__attribute__((address_space(3))) unsigned int*)s,
        16, 0, 0);
}

// ---- main: 6-term split GEMM + fused softmax/top-8 ----
// Block = 512 thr = 8 waves. wave wv: row-group wq = wv&3 (16 rows), K-half
// h = wv>>2 (1024 k-elems, 32 k-steps). Grid = 512 blocks (64 rows each).
// 16 waves/CU (2 blocks/CU), LDS 48 KB (3 blocks/CU possible by LDS).
__global__ __launch_bounds__(512, 4) void moe_gate(const float* __restrict__ r,
                                                   const __bf16* __restrict__ P,
                                                   const float* __restrict__ bias,
                                                   float* __restrict__ out) {
    // union: bstage [half][dbuf][split][2048 bf16] = 48 KB  |  lg[64][65] f32
    // (16.6 KB). Disjoint in time: bstage during K-loop, lg after.
    __shared__ __align__(16) char smem[2 * 2 * 3 * 2048 * 2];   // 49152 B

    __bf16 (*bstage)[2][3][2048] = reinterpret_cast<__bf16 (*)[2][3][2048]>(smem);
    float  (*lg)[E_DIM + 1]      = reinterpret_cast<float (*)[E_DIM + 1]>(smem);

    const int t    = threadIdx.x;
    const int wv   = t >> 6;
    const int lane = t & 63;
    const int lrow = lane & 15;
    const int quad = lane >> 4;
    const int h    = wv >> 2;    // K half
    const int wq   = wv & 3;     // row group
    const int tl   = t & 255;    // slot within half-group (256 threads stage 12 KB)
    const int row0 = blockIdx.x * 64;

    // staging source: contiguous per wave. global kstep = h*32 + local ks.
    const __bf16* Pb = P + (size_t)h * 32 * 6144 + tl * 8;

    const float* ra = r + (size_t)(row0 + wq * 16 + lrow) * D_DIM + h * 1024 + quad * 8;

    f32x4 accM[4] = {};  // h1*g1              (~1)
    f32x4 accD[4] = {};  // h1*g2 + h2*g1      (~2^-8)
    f32x4 accL[4] = {};  // h1*g3+h2*g2+h3*g1  (~2^-16)

    // prologue: stage local k-step 0, load A(0)
    #pragma unroll
    for (int s = 0; s < 3; ++s)
        gload_lds16(Pb + s * 2048, &bstage[h][0][s][tl * 8]);
    float4 a0 = *(const float4*)(ra);
    float4 a1 = *(const float4*)(ra + 4);

    for (int ks = 0; ks < 32; ++ks) {
        __syncthreads();  // bstage[h][ks&1] written; prior reads of other buf done
        const int kn = ks + 1;
        if (kn < 32) {    // stage next local k-step into other buffer (async)
            #pragma unroll
            for (int s = 0; s < 3; ++s)
                gload_lds16(Pb + (size_t)kn * 6144 + s * 2048,
                            &bstage[h][kn & 1][s][tl * 8]);
        }

        // split current A; prefetch next A into registers
        float av[8] = {a0.x, a0.y, a0.z, a0.w, a1.x, a1.y, a1.z, a1.w};
        if (kn < 32) {
            a0 = *(const float4*)(ra + kn * 32);
            a1 = *(const float4*)(ra + kn * 32 + 4);
        }
        bf16x8 A1, A2, A3;
        #pragma unroll
        for (int j = 0; j < 8; ++j) {
            float x  = av[j];
            __bf16 h1 = (__bf16)x;
            float r1 = x - (float)h1;
            __bf16 h2 = (__bf16)r1;
            float r2 = r1 - (float)h2;
            A1[j] = h1; A2[j] = h2; A3[j] = (__bf16)r2;
        }

        // all 12 B fragments up front (ds_read_b128 burst, high MLP)
        const __bf16* bb = &bstage[h][ks & 1][0][0];
        const int fo = quad * 8 + lrow * 32;  // within a split-tile
        bf16x8 B[3][4];
        #pragma unroll
        for (int s = 0; s < 3; ++s)
            #pragma unroll
            for (int n = 0; n < 4; ++n)
                B[s][n] = *(const bf16x8*)(bb + (size_t)s * 2048 + n * 512 + fo);

        #pragma unroll
        for (int n = 0; n < 4; ++n) {
            accM[n] = __builtin_amdgcn_mfma_f32_16x16x32_bf16(A1, B[0][n], accM[n], 0, 0, 0);
            accD[n] = __builtin_amdgcn_mfma_f32_16x16x32_bf16(A1, B[1][n], accD[n], 0, 0, 0);
            accD[n] = __builtin_amdgcn_mfma_f32_16x16x32_bf16(A2, B[0][n], accD[n], 0, 0, 0);
            accL[n] = __builtin_amdgcn_mfma_f32_16x16x32_bf16(A1, B[2][n], accL[n], 0, 0, 0);
            accL[n] = __builtin_amdgcn_mfma_f32_16x16x32_bf16(A2, B[1][n], accL[n], 0, 0, 0);
            accL[n] = __builtin_amdgcn_mfma_f32_16x16x32_bf16(A3, B[0][n], accL[n], 0, 0, 0);
        }
    }

    __syncthreads();  // all waves done reading bstage; safe to reuse smem as lg

    // C/D layout: col = lane&15, row = quad*4 + reg. Combine small-first.
    // Two-phase K-half reduction: half 0 writes, half 1 accumulates.
    if (h == 0) {
        #pragma unroll
        for (int n = 0; n < 4; ++n) {
            int col = n * 16 + lrow;
            #pragma unroll
            for (int i = 0; i < 4; ++i)
                lg[wq * 16 + quad * 4 + i][col] = accM[n][i] + (accD[n][i] + accL[n][i]);
        }
    }
    __syncthreads();
    if (h == 1) {
        #pragma unroll
        for (int n = 0; n < 4; ++n) {
            int col = n * 16 + lrow;
            #pragma unroll
            for (int i = 0; i < 4; ++i)
                lg[wq * 16 + quad * 4 + i][col] += accM[n][i] + (accD[n][i] + accL[n][i]);
        }
    }
    __syncthreads();

    // softmax + top-8; wave per row, lane = expert. TEMPERATURE == 1.0.
    const float bcol = bias[lane];
    for (int rr = wv; rr < 64; rr += 8) {
        float logit = lg[rr][lane] + bcol;
        float mx = logit;
        #pragma unroll
        for (int s = 32; s >= 1; s >>= 1) mx = fmaxf(mx, __shfl_xor(mx, s));
        float ex = expf(logit - mx);
        float sm = ex;
        #pragma unroll
        for (int s = 32; s >= 1; s >>= 1) sm += __shfl_xor(sm, s);
        float soft = ex / sm;

        // top-8 on soft (monotone in logit); lowest-index tie-break = lax.top_k
        bool  sel    = false;
        float topsum = 0.0f;
        #pragma unroll
        for (int it = 0; it < TOPK; ++it) {
            float cand = sel ? -1.0f : soft;  // soft > 0 always
            float cm = cand;
            #pragma unroll
            for (int s = 32; s >= 1; s >>= 1) cm = fmaxf(cm, __shfl_xor(cm, s));
            unsigned long long ball = __ballot(cand == cm);
            int leader = __ffsll(ball) - 1;
            if (lane == leader) sel = true;
            topsum += cm;
        }
        float hard = sel ? soft / (topsum + 1e-9f) : 0.0f;

        size_t orow = (size_t)(row0 + rr) * E_DIM + lane;
        out[orow] = hard;
        out[(size_t)B_DIM * E_DIM + orow] = soft;
    }
}

extern "C" void kernel_launch(void* const* d_in, const int* in_sizes, int n_in,
                              void* d_out, int out_size, void* d_ws, size_t ws_size,
                              hipStream_t stream) {
    const float* r = (const float*)d_in[0];
    const float* W = (const float*)d_in[1];
    const float* b = (const float*)d_in[2];
    float* out = (float*)d_out;
    __bf16* P = (__bf16*)d_ws;   // 64 ksteps * 12 KB = 768 KB of ws

    w_prep<<<64, 256, 0, stream>>>(W, P);
    moe_gate<<<512, 512, 0, stream>>>(r, P, b, out);
}